// Round 2
// baseline (29675.671 us; speedup 1.0000x reference)
//
#include <hip/hip_runtime.h>
#include <hip/hip_fp16.h>
#include <hip/hip_cooperative_groups.h>

#define B_ 512
#define T_ 256
#define H_ 1024
#define G4_ 4096

typedef _Float16 half8 __attribute__((ext_vector_type(8)));
typedef float f32x4 __attribute__((ext_vector_type(4)));

__device__ __forceinline__ float fast_sigmoid(float x) {
    return 1.0f / (1.0f + __expf(-x));
}
__device__ __forceinline__ float fast_tanh(float x) {
    float x2 = fminf(fmaxf(2.0f * x, -30.0f), 30.0f);
    float e = __expf(x2);
    return (e - 1.0f) / (e + 1.0f);
}

// Repack W_hh [4096 x 1024] fp32 -> fp16 in MFMA B-fragment order:
// Wp[((j*32 + ki)*4 + nt)*64*8 + l*8 + e] = W_hh[gc][k]
//   gc = nt*1024 + j*16 + (l&15),  k = ki*32 + (l>>4)*8 + e
__global__ void pack_w(const float* __restrict__ Whh, _Float16* __restrict__ Wp) {
    int idx = blockIdx.x * blockDim.x + threadIdx.x;   // over 4096*1024
    int gc = idx >> 10, k = idx & 1023;
    int nt = gc >> 10, khid = gc & 1023;
    int j = khid >> 4, lk = khid & 15;
    int ki = k >> 5, hi = (k >> 3) & 3, e = k & 7;
    int l = hi * 16 + lk;
    Wp[(((((j * 32 + ki) * 4 + nt) * 64) + l) << 3) + e] = (_Float16)Whh[idx];
}

__global__ void init_misc(const float* __restrict__ bih, const float* __restrict__ bhh,
                          const float* __restrict__ bout,
                          float* __restrict__ bias, float* __restrict__ out) {
    int idx = blockIdx.x * blockDim.x + threadIdx.x;   // 131072 threads
    if (idx < G4_) bias[idx] = bih[idx] + bhh[idx];
    if (idx < B_ * T_) out[idx] = bout[0];
}

// Persistent cooperative kernel: 256 WGs x 512 threads, one WG per CU.
// WG -> (batch tile i of 128 rows, hidden tile j of 16 units -> 64 gate cols).
// W_hh slice lives in LDS (128 KB); c lives in 4 VGPRs/thread; grid.sync per step.
__global__ __launch_bounds__(512, 1)
void lstm_persist(const _Float16* __restrict__ Wp,
                  const float* __restrict__ bias,
                  const float* __restrict__ x,
                  const float* __restrict__ Wih,
                  const float* __restrict__ Wout,
                  _Float16* __restrict__ hA,
                  _Float16* __restrict__ hB,
                  float* __restrict__ out) {
    extern __shared__ _Float16 Wl[];   // 65536 halves = 128 KB
    cooperative_groups::grid_group grid = cooperative_groups::this_grid();

    const int blk = blockIdx.x;
    // XCD-locality: all 4 batch-tiles of a given j land on the same XCD
    const int j = (blk & 7) * 8 + ((blk >> 3) & 7);   // hidden tile [0,64)
    const int i = blk >> 6;                            // batch tile [0,4)
    const int tid = threadIdx.x;
    const int w = tid >> 6, l = tid & 63;
    const int lk = l & 15, hi = l >> 4;
    const int rowbase = i * 128 + w * 16;
    const int khid = j * 16 + lk;

    // one-time: copy this WG's W slice (65536 halves) into LDS
    {
        const half8* src = (const half8*)(Wp + (size_t)j * 65536);
        half8* dst = (half8*)Wl;
#pragma unroll
        for (int o = 0; o < 16; ++o) dst[tid + o * 512] = src[tid + o * 512];
    }
    // one-time: per-thread constants
    float bz[4], wi4[4];
#pragma unroll
    for (int nt = 0; nt < 4; ++nt) {
        int gc = nt * 1024 + khid;
        bz[nt] = bias[gc];
        wi4[nt] = Wih[gc];
    }
    const float wout = Wout[khid];
    int rows[4];
#pragma unroll
    for (int r = 0; r < 4; ++r) rows[r] = rowbase + hi * 4 + r;
    f32x4 creg = {0.f, 0.f, 0.f, 0.f};
    __syncthreads();

    const size_t aoff = ((size_t)(hi * 512) + rowbase + lk) * 8;

    for (int t = 0; t < T_; ++t) {
        const _Float16* hp = (t & 1) ? hB : hA;
        _Float16* hn = (t & 1) ? hA : hB;

        f32x4 acc[4];
        float xv[4];
#pragma unroll
        for (int r = 0; r < 4; ++r) xv[r] = x[rows[r] * T_ + t];
#pragma unroll
        for (int nt = 0; nt < 4; ++nt) {
#pragma unroll
            for (int r = 0; r < 4; ++r) acc[nt][r] = bz[nt] + xv[r] * wi4[nt];
        }

        const _Float16* Ap = hp + aoff;
#pragma unroll 8
        for (int ki = 0; ki < 32; ++ki) {
            half8 a = *(const half8*)(Ap + (size_t)ki * (4 * 512 * 8));
            const _Float16* bp = Wl + ki * (4 * 64 * 8) + l * 8;
#pragma unroll
            for (int nt = 0; nt < 4; ++nt) {
                half8 b = *(const half8*)(bp + nt * (64 * 8));
                acc[nt] = __builtin_amdgcn_mfma_f32_16x16x32_f16(a, b, acc[nt], 0, 0, 0);
            }
        }

        // elementwise LSTM update; acc[0..3] = i,f,g,o pre-activations
        float p4[4];
#pragma unroll
        for (int r = 0; r < 4; ++r) {
            float iv = fast_sigmoid(acc[0][r]);
            float fv = fast_sigmoid(acc[1][r]);
            float gv = fast_tanh(acc[2][r]);
            float ov = fast_sigmoid(acc[3][r]);
            float cv = fv * creg[r] + iv * gv;
            creg[r] = cv;
            float hv = ov * fast_tanh(cv);
            hn[(((size_t)(khid >> 3) * 512 + rows[r]) << 3) + (khid & 7)] = (_Float16)hv;
            p4[r] = hv * wout;
        }
        // reduce across the 16 lanes (lk) sharing the same rows
#pragma unroll
        for (int mask = 1; mask <= 8; mask <<= 1) {
#pragma unroll
            for (int r = 0; r < 4; ++r) p4[r] += __shfl_xor(p4[r], mask);
        }
        if (lk == 0) {
#pragma unroll
            for (int r = 0; r < 4; ++r)
                atomicAdd(&out[rows[r] * T_ + t], p4[r]);
        }

        __threadfence();   // release: h writes -> visible device-wide
        grid.sync();
        __threadfence();   // acquire: invalidate stale L1/L2 lines before next read
    }
}

extern "C" void kernel_launch(void* const* d_in, const int* in_sizes, int n_in,
                              void* d_out, int out_size, void* d_ws, size_t ws_size,
                              hipStream_t stream) {
    const float* x    = (const float*)d_in[0];
    const float* Wih  = (const float*)d_in[1];
    const float* Whh  = (const float*)d_in[2];
    const float* bih  = (const float*)d_in[3];
    const float* bhh  = (const float*)d_in[4];
    const float* Wout = (const float*)d_in[5];
    const float* bout = (const float*)d_in[6];
    float* out = (float*)d_out;

    char* ws = (char*)d_ws;
    _Float16* Wp = (_Float16*)ws;                         // 8 MB packed W_hh
    _Float16* hA = (_Float16*)(ws + (8 << 20));           // 1 MB h ping
    _Float16* hB = (_Float16*)(ws + (9 << 20));           // 1 MB h pong
    float* bias  = (float*)(ws + (10 << 20));             // 16 KB

    // zero both h buffers
    hipMemsetAsync(ws + (8 << 20), 0, 2 << 20, stream);

    pack_w<<<(G4_ * H_) / 256, 256, 0, stream>>>(Whh, Wp);
    init_misc<<<512, 256, 0, stream>>>(bih, bhh, bout, bias, out);

    void* args[] = {&Wp, &bias, &x, &Wih, &Wout, &hA, &hB, &out};
    hipLaunchCooperativeKernel((void*)lstm_persist, dim3(256), dim3(512),
                               args, 131072, stream);
}

// Round 3
// 5733.640 us; speedup vs baseline: 5.1757x; 5.1757x over previous
//
#include <hip/hip_runtime.h>
#include <hip/hip_fp16.h>
#include <hip/hip_cooperative_groups.h>

#define B_ 512
#define T_ 256
#define H_ 1024
#define G4_ 4096

typedef _Float16 half8 __attribute__((ext_vector_type(8)));
typedef float f32x4 __attribute__((ext_vector_type(4)));

__device__ __forceinline__ float fast_sigmoid(float x) {
    return 1.0f / (1.0f + __expf(-x));
}
__device__ __forceinline__ float fast_tanh(float x) {
    float x2 = fminf(fmaxf(2.0f * x, -30.0f), 30.0f);
    float e = __expf(x2);
    return (e - 1.0f) / (e + 1.0f);
}

// Repack W_hh [4096 x 1024] fp32 -> fp16 MFMA B-fragment order (same map as r0):
// Wp[j*65536 + ki*2048 + nt*512 + l*8 + e], j = u>>4 (u = hidden unit),
//   gc = nt*1024 + u, lk = u&15, ki = k>>5, hi = (k>>3)&3, e = k&7, l = hi*16+lk
__global__ void pack_w(const float* __restrict__ Whh, _Float16* __restrict__ Wp) {
    int idx = blockIdx.x * blockDim.x + threadIdx.x;   // over 4096*1024
    int gc = idx >> 10, k = idx & 1023;
    int nt = gc >> 10, u = gc & 1023;
    int j = u >> 4, lk = u & 15;
    int ki = k >> 5, hi = (k >> 3) & 3, e = k & 7;
    int l = hi * 16 + lk;
    Wp[(size_t)j * 65536 + ki * 2048 + nt * 512 + l * 8 + e] = (_Float16)Whh[idx];
}

__global__ void init_misc(const float* __restrict__ bih, const float* __restrict__ bhh,
                          const float* __restrict__ bout,
                          float* __restrict__ bias, float* __restrict__ out) {
    int idx = blockIdx.x * blockDim.x + threadIdx.x;   // 131072 threads
    if (idx < G4_) bias[idx] = bih[idx] + bhh[idx];
    if (idx < B_ * T_) out[idx] = bout[0];
}

// Persistent kernel, 256 WGs x 512 thr (1 WG/CU). Batch partitioned across
// XCDs (64 rows each) -> NO cross-XCD communication ever. Within an XCD,
// 32 WGs each own 32 hidden units (128 gate cols); W k-half in LDS (128 KB),
// other half L2-resident (4 MB/XCD). h triple-buffered per XCD; XCD-local
// atomic barrier + L1-only invalidate per step. c lives in VGPRs.
__global__ __launch_bounds__(512, 1)
void lstm_persist(const _Float16* __restrict__ Wp,
                  const float* __restrict__ bias,
                  const float* __restrict__ x,
                  const float* __restrict__ Wih,
                  const float* __restrict__ Wout,
                  _Float16* __restrict__ hbuf,        // [8 xcd][3 phase][65536 halves]
                  float* __restrict__ out,
                  unsigned int* __restrict__ cnts) {  // [0..7] slot, [16 + xcd*32] barrier
    extern __shared__ _Float16 Wl[];   // 65536 halves = 128 KB
    __shared__ int sh_xcd, sh_slot;
    cooperative_groups::grid_group grid = cooperative_groups::this_grid();

    const int tid = threadIdx.x;
    if (tid == 0) {
        unsigned int xcc;
        asm volatile("s_getreg_b32 %0, hwreg(HW_REG_XCC_ID)" : "=s"(xcc));
        xcc &= 7u;
        sh_xcd = (int)xcc;
        sh_slot = (int)__hip_atomic_fetch_add(&cnts[xcc], 1u,
                                              __ATOMIC_RELAXED, __HIP_MEMORY_SCOPE_AGENT);
    }
    __syncthreads();
    const int xcd = sh_xcd, slot = sh_slot;
    // one-time registration sync (cheap; makes under-filled XCDs fail visibly, not hang)
    grid.sync();
    const int nactive = (int)min(32u, cnts[xcd]);   // barrier population for this XCD
    if (slot >= 32) return;

    const int w = tid >> 6, l = tid & 63;
    const int lk = l & 15, hi = l >> 4;
    const int wr = w >> 1, wj = w & 1;        // 4 row-blocks x 2 u-blocks
    const int row0 = wr * 16;                 // local row base (0..48)
    const int u = slot * 32 + wj * 16 + lk;   // hidden unit for this lane

    // one-time: W k-half [0,512) -> LDS (2 chunks of 4096 half8 per j-block)
    {
        const half8* src = (const half8*)Wp + (size_t)slot * 16384;  // slot*2 j-blocks
        half8* dst = (half8*)Wl;
#pragma unroll
        for (int it = 0; it < 16; ++it) {
            int i16 = tid + it * 512;          // 0..8191
            int j2 = i16 >> 12, r = i16 & 4095;
            dst[j2 * 4096 + r] = src[j2 * 8192 + r];
        }
    }
    // one-time per-thread constants
    float bz[4], wi4[4];
#pragma unroll
    for (int nt = 0; nt < 4; ++nt) {
        int gc = nt * 1024 + u;
        bz[nt] = bias[gc];
        wi4[nt] = Wih[gc];
    }
    const float wout = Wout[u];
    int rowsl[4], rowsg[4];
#pragma unroll
    for (int r = 0; r < 4; ++r) {
        rowsl[r] = row0 + hi * 4 + r;
        rowsg[r] = xcd * 64 + rowsl[r];
    }
    const int kb = u >> 3, ue = u & 7;
    f32x4 creg = {0.f, 0.f, 0.f, 0.f};
    __syncthreads();

    _Float16* hx = hbuf + (size_t)xcd * 3 * 65536;
    const _Float16* Bg = Wp + ((size_t)slot * 2 + wj) * 65536 + l * 8;
    unsigned int* barp = &cnts[16 + xcd * 32];

    int rp = 0, wp = 1;
    for (int t = 0; t < T_; ++t) {
        f32x4 acc[4];
        float xv[4];
#pragma unroll
        for (int r = 0; r < 4; ++r) xv[r] = x[rowsg[r] * T_ + t];
#pragma unroll
        for (int nt = 0; nt < 4; ++nt) {
#pragma unroll
            for (int r = 0; r < 4; ++r) acc[nt][r] = bz[nt] + xv[r] * wi4[nt];
        }

        if (t > 0) {
            const _Float16* Ap = hx + rp * 65536 + hi * 512 + (row0 + lk) * 8;
            // k-half 0: B from LDS
#pragma unroll
            for (int ki = 0; ki < 16; ++ki) {
                half8 a = *(const half8*)(Ap + ki * 2048);
                const _Float16* bp = Wl + wj * 32768 + ki * 2048 + l * 8;
#pragma unroll
                for (int nt = 0; nt < 4; ++nt) {
                    half8 b = *(const half8*)(bp + nt * 512);
                    acc[nt] = __builtin_amdgcn_mfma_f32_16x16x32_f16(a, b, acc[nt], 0, 0, 0);
                }
            }
            // k-half 1: B from L2-resident global
#pragma unroll
            for (int ki = 16; ki < 32; ++ki) {
                half8 a = *(const half8*)(Ap + ki * 2048);
                const _Float16* bp = Bg + ki * 2048;
#pragma unroll
                for (int nt = 0; nt < 4; ++nt) {
                    half8 b = *(const half8*)(bp + nt * 512);
                    acc[nt] = __builtin_amdgcn_mfma_f32_16x16x32_f16(a, b, acc[nt], 0, 0, 0);
                }
            }
        }

        // elementwise LSTM update; acc[0..3] = i,f,g,o
        _Float16* hn = hx + wp * 65536;
        float p4[4];
#pragma unroll
        for (int r = 0; r < 4; ++r) {
            float iv = fast_sigmoid(acc[0][r]);
            float fv = fast_sigmoid(acc[1][r]);
            float gv = fast_tanh(acc[2][r]);
            float ov = fast_sigmoid(acc[3][r]);
            float cv = fv * creg[r] + iv * gv;
            creg[r] = cv;
            float hv = ov * fast_tanh(cv);
            hn[(kb * 64 + rowsl[r]) * 8 + ue] = (_Float16)hv;
            p4[r] = hv * wout;
        }
#pragma unroll
        for (int m = 1; m <= 8; m <<= 1) {
#pragma unroll
            for (int r = 0; r < 4; ++r) p4[r] += __shfl_xor(p4[r], m);
        }
        if (lk == 0) {
#pragma unroll
            for (int r = 0; r < 4; ++r)
                atomicAdd(&out[rowsg[r] * T_ + t], p4[r]);
        }

        if (t < T_ - 1) {
            // XCD-local barrier: syncthreads drains this WG's vmem (stores now in
            // this XCD's shared L2); one lane arrives + spins; L1-only invalidate.
            __syncthreads();
            if (tid == 0) {
                __hip_atomic_fetch_add(barp, 1u, __ATOMIC_RELAXED, __HIP_MEMORY_SCOPE_AGENT);
                unsigned int tgt = (unsigned int)nactive * (unsigned int)(t + 1);
                while (__hip_atomic_load(barp, __ATOMIC_RELAXED, __HIP_MEMORY_SCOPE_AGENT) < tgt)
                    __builtin_amdgcn_s_sleep(2);
            }
            __syncthreads();
            asm volatile("buffer_inv sc0" ::: "memory");   // drop stale L1 lines
        }
        rp = wp;
        wp = (wp == 2) ? 0 : wp + 1;
    }
}

extern "C" void kernel_launch(void* const* d_in, const int* in_sizes, int n_in,
                              void* d_out, int out_size, void* d_ws, size_t ws_size,
                              hipStream_t stream) {
    const float* x    = (const float*)d_in[0];
    const float* Wih  = (const float*)d_in[1];
    const float* Whh  = (const float*)d_in[2];
    const float* bih  = (const float*)d_in[3];
    const float* bhh  = (const float*)d_in[4];
    const float* Wout = (const float*)d_in[5];
    const float* bout = (const float*)d_in[6];
    float* out = (float*)d_out;

    char* ws = (char*)d_ws;
    _Float16* Wp   = (_Float16*)ws;                        // 8 MB packed W_hh
    _Float16* hbuf = (_Float16*)(ws + (8 << 20));          // 3 MB h (8 xcd x 3 phase)
    float* bias    = (float*)(ws + (11 << 20));            // 16 KB
    unsigned int* cnts = (unsigned int*)(ws + (11 << 20) + (64 << 10));  // 4 KB

    hipMemsetAsync(cnts, 0, 4096, stream);
    pack_w<<<(G4_ * H_) / 256, 256, 0, stream>>>(Whh, Wp);
    init_misc<<<512, 256, 0, stream>>>(bih, bhh, bout, bias, out);

    void* args[] = {&Wp, &bias, &x, &Wih, &Wout, &hbuf, &out, &cnts};
    hipLaunchCooperativeKernel((void*)lstm_persist, dim3(256), dim3(512),
                               args, 131072, stream);
}

// Round 5
// 2081.978 us; speedup vs baseline: 14.2536x; 2.7539x over previous
//
#include <hip/hip_runtime.h>
#include <hip/hip_fp16.h>
#include <hip/hip_cooperative_groups.h>

#define B_ 512
#define T_ 256
#define H_ 1024
#define G4_ 4096
#define KL_ 20   // k-slices (of 32) resident in LDS
#define KG_ 12   // k-slices from L2

typedef _Float16 half8 __attribute__((ext_vector_type(8)));
typedef float f32x4 __attribute__((ext_vector_type(4)));

__device__ __forceinline__ float fast_sigmoid(float x) {
    return 1.0f / (1.0f + __expf(-x));
}
__device__ __forceinline__ float fast_tanh(float x) {
    float x2 = fminf(fmaxf(2.0f * x, -30.0f), 30.0f);
    float e = __expf(x2);
    return (e - 1.0f) / (e + 1.0f);
}

// Repack W_hh [4096 x 1024] fp32 -> fp16 MFMA B-fragment order, split into
// W_lds (ki 0..19, per slot 81920 halves, read once at startup) and
// W_l2 (ki 20..31, per j-block 24576 halves; hot set = 3 MB/XCD).
__global__ void pack_w(const float* __restrict__ Whh,
                       _Float16* __restrict__ Wlds, _Float16* __restrict__ Wl2) {
    int idx = blockIdx.x * blockDim.x + threadIdx.x;   // over 4096*1024
    int gc = idx >> 10, k = idx & 1023;
    int nt = gc >> 10, u = gc & 1023;
    int jb = u >> 4, lk = u & 15;
    int ki = k >> 5, hi = (k >> 3) & 3, e = k & 7;
    int l = hi * 16 + lk;
    _Float16 v = (_Float16)Whh[idx];
    int frag = nt * 512 + l * 8 + e;
    if (ki < KL_) {
        int slot = jb >> 1, wj = jb & 1;
        Wlds[(size_t)slot * 81920 + wj * 40960 + ki * 2048 + frag] = v;
    } else {
        Wl2[(size_t)jb * 24576 + (ki - KL_) * 2048 + frag] = v;
    }
}

__global__ void init_misc(const float* __restrict__ bih, const float* __restrict__ bhh,
                          const float* __restrict__ bout,
                          float* __restrict__ bias, float* __restrict__ out) {
    int idx = blockIdx.x * blockDim.x + threadIdx.x;   // 131072 threads
    if (idx < G4_) bias[idx] = bih[idx] + bhh[idx];
    if (idx < B_ * T_) out[idx] = bout[0];
}

// Persistent kernel, 256 WGs x 512 thr (1 WG/CU). Batch across XCDs (64 rows
// each, zero cross-XCD traffic). Per XCD: 32 WGs x 32 hidden units; W ki 0..19
// in LDS (exactly 160 KB dynamic, NO static shared), ki 20..31 from a dense
// 3 MB L2-hot array. h double-buffered; c in VGPRs; XCD-local atomic barrier
// + L1-only invalidate per step.
__global__ __launch_bounds__(512, 1)
void lstm_persist(const _Float16* __restrict__ Wlds,
                  const _Float16* __restrict__ Wl2,
                  const float* __restrict__ bias,
                  const float* __restrict__ x,
                  const float* __restrict__ Wih,
                  const float* __restrict__ Wout,
                  _Float16* __restrict__ hbuf,        // [8 xcd][2 phase][65536 halves]
                  float* __restrict__ out,
                  unsigned int* __restrict__ cnts) {  // [xcd] slot ctr, [16+xcd*32] barrier,
                                                      // [512+blk] slotmap
    extern __shared__ _Float16 Wl[];   // 81920 halves = 160 KB (full CU LDS)
    cooperative_groups::grid_group grid = cooperative_groups::this_grid();

    const int tid = threadIdx.x;
    unsigned int xcc;
    asm volatile("s_getreg_b32 %0, hwreg(HW_REG_XCC_ID)" : "=s"(xcc));
    const int xcd = (int)(xcc & 7u);
    if (tid == 0) {
        unsigned int s = __hip_atomic_fetch_add(&cnts[xcd], 1u,
                                                __ATOMIC_RELAXED, __HIP_MEMORY_SCOPE_AGENT);
        __hip_atomic_store(&cnts[512 + blockIdx.x], s,
                           __ATOMIC_RELAXED, __HIP_MEMORY_SCOPE_AGENT);
    }
    grid.sync();   // one-time registration sync (also publishes slotmap)
    const int slot = (int)__hip_atomic_load(&cnts[512 + blockIdx.x],
                                            __ATOMIC_RELAXED, __HIP_MEMORY_SCOPE_AGENT);
    const int nactive = (int)min(32u, __hip_atomic_load(&cnts[xcd], __ATOMIC_RELAXED,
                                                        __HIP_MEMORY_SCOPE_AGENT));
    if (slot >= 32) return;

    const int w = tid >> 6, l = tid & 63;
    const int lk = l & 15, hi = l >> 4;
    const int wr = w >> 1, wj = w & 1;        // 4 row-blocks x 2 u-blocks
    const int row0 = wr * 16;                 // local row base (0..48)
    const int u = slot * 32 + wj * 16 + lk;   // hidden unit for this lane

    // one-time: this slot's W ki 0..19 -> LDS (81920 halves = 10240 half8)
    {
        const half8* src = (const half8*)(Wlds + (size_t)slot * 81920);
        half8* dst = (half8*)Wl;
#pragma unroll
        for (int o = 0; o < 20; ++o) dst[tid + o * 512] = src[tid + o * 512];
    }
    // one-time per-thread constants
    float bz[4], wi4[4];
#pragma unroll
    for (int nt = 0; nt < 4; ++nt) {
        int gc = nt * 1024 + u;
        bz[nt] = bias[gc];
        wi4[nt] = Wih[gc];
    }
    const float wout = Wout[u];
    int rowsl[4], rowsg[4];
#pragma unroll
    for (int r = 0; r < 4; ++r) {
        rowsl[r] = row0 + hi * 4 + r;
        rowsg[r] = xcd * 64 + rowsl[r];
    }
    const int kb = u >> 3, ue = u & 7;
    f32x4 creg = {0.f, 0.f, 0.f, 0.f};
    __syncthreads();

    _Float16* hx = hbuf + (size_t)xcd * 2 * 65536;
    const _Float16* Bg = Wl2 + ((size_t)slot * 2 + wj) * 24576 + l * 8;
    unsigned int* barp = &cnts[16 + xcd * 32];

    for (int t = 0; t < T_; ++t) {
        const int wb = t & 1, rb = wb ^ 1;
        f32x4 acc[4];
        float xv[4];
#pragma unroll
        for (int r = 0; r < 4; ++r) xv[r] = x[rowsg[r] * T_ + t];
#pragma unroll
        for (int nt = 0; nt < 4; ++nt) {
#pragma unroll
            for (int r = 0; r < 4; ++r) acc[nt][r] = bz[nt] + xv[r] * wi4[nt];
        }

        if (t > 0) {
            const _Float16* Ap = hx + rb * 65536 + hi * 512 + (row0 + lk) * 8;
            // k-slices 20..31: B from dense L2-hot global (loads issue early)
#pragma unroll
            for (int kg = 0; kg < KG_; ++kg) {
                half8 a = *(const half8*)(Ap + (KL_ + kg) * 2048);
                const _Float16* bp = Bg + kg * 2048;
#pragma unroll
                for (int nt = 0; nt < 4; ++nt) {
                    half8 b = *(const half8*)(bp + nt * 512);
                    acc[nt] = __builtin_amdgcn_mfma_f32_16x16x32_f16(a, b, acc[nt], 0, 0, 0);
                }
            }
            // k-slices 0..19: B from LDS
#pragma unroll
            for (int ki = 0; ki < KL_; ++ki) {
                half8 a = *(const half8*)(Ap + ki * 2048);
                const _Float16* bp = Wl + wj * 40960 + ki * 2048 + l * 8;
#pragma unroll
                for (int nt = 0; nt < 4; ++nt) {
                    half8 b = *(const half8*)(bp + nt * 512);
                    acc[nt] = __builtin_amdgcn_mfma_f32_16x16x32_f16(a, b, acc[nt], 0, 0, 0);
                }
            }
        }

        // elementwise LSTM update; acc[0..3] = i,f,g,o
        _Float16* hn = hx + wb * 65536;
        float p4[4];
#pragma unroll
        for (int r = 0; r < 4; ++r) {
            float iv = fast_sigmoid(acc[0][r]);
            float fv = fast_sigmoid(acc[1][r]);
            float gv = fast_tanh(acc[2][r]);
            float ov = fast_sigmoid(acc[3][r]);
            float cv = fv * creg[r] + iv * gv;
            creg[r] = cv;
            float hv = ov * fast_tanh(cv);
            hn[(kb * 64 + rowsl[r]) * 8 + ue] = (_Float16)hv;
            p4[r] = hv * wout;
        }
#pragma unroll
        for (int m = 1; m <= 8; m <<= 1) {
#pragma unroll
            for (int r = 0; r < 4; ++r) p4[r] += __shfl_xor(p4[r], m);
        }
        if (lk == 0) {
#pragma unroll
            for (int r = 0; r < 4; ++r)
                atomicAdd(&out[rowsg[r] * T_ + t], p4[r]);
        }

        if (t < T_ - 1) {
            // XCD-local barrier: syncthreads drains this WG's vmem into the
            // XCD's L2; one lane arrives + spins; then L1-only invalidate.
            __syncthreads();
            if (tid == 0) {
                __hip_atomic_fetch_add(barp, 1u, __ATOMIC_RELAXED, __HIP_MEMORY_SCOPE_AGENT);
                unsigned int tgt = (unsigned int)nactive * (unsigned int)(t + 1);
                while (__hip_atomic_load(barp, __ATOMIC_RELAXED, __HIP_MEMORY_SCOPE_AGENT) < tgt)
                    __builtin_amdgcn_s_sleep(2);
            }
            __syncthreads();
            asm volatile("buffer_inv sc0" ::: "memory");   // drop stale L1 lines
        }
    }
}

extern "C" void kernel_launch(void* const* d_in, const int* in_sizes, int n_in,
                              void* d_out, int out_size, void* d_ws, size_t ws_size,
                              hipStream_t stream) {
    const float* x    = (const float*)d_in[0];
    const float* Wih  = (const float*)d_in[1];
    const float* Whh  = (const float*)d_in[2];
    const float* bih  = (const float*)d_in[3];
    const float* bhh  = (const float*)d_in[4];
    const float* Wout = (const float*)d_in[5];
    const float* bout = (const float*)d_in[6];
    float* out = (float*)d_out;

    char* ws = (char*)d_ws;
    _Float16* Wlds = (_Float16*)ws;                        // 5 MB (32 x 160 KB)
    _Float16* Wl2  = (_Float16*)(ws + 5242880);            // 3 MB (64 x 48 KB)
    _Float16* hbuf = (_Float16*)(ws + (8 << 20));          // 2 MB (8 xcd x 2 x 128 KB)
    float* bias    = (float*)(ws + (10 << 20));            // 16 KB
    unsigned int* cnts = (unsigned int*)(ws + (10 << 20) + (64 << 10));  // 4 KB

    hipMemsetAsync(cnts, 0, 4096, stream);
    pack_w<<<(G4_ * H_) / 256, 256, 0, stream>>>(Whh, Wlds, Wl2);
    init_misc<<<512, 256, 0, stream>>>(bih, bhh, bout, bias, out);

    (void)hipFuncSetAttribute((const void*)lstm_persist,
                              hipFuncAttributeMaxDynamicSharedMemorySize, 163840);
    void* args[] = {&Wlds, &Wl2, &bias, &x, &Wih, &Wout, &hbuf, &out, &cnts};
    hipLaunchCooperativeKernel((void*)lstm_persist, dim3(256), dim3(512),
                               args, 163840, stream);
}

// Round 6
// 1880.801 us; speedup vs baseline: 15.7782x; 1.1070x over previous
//
#include <hip/hip_runtime.h>
#include <hip/hip_fp16.h>
#include <hip/hip_cooperative_groups.h>

#define B_ 512
#define T_ 256
#define H_ 1024
#define G4_ 4096
#define KL_ 20   // k-slices (of 32) resident in LDS
#define KR_ 8    // k-slices pinned in registers (ki 20..27)
#define KS_ 4    // k-slices streamed from L2 (ki 28..31)

typedef _Float16 half8 __attribute__((ext_vector_type(8)));
typedef float f32x4 __attribute__((ext_vector_type(4)));

__device__ __forceinline__ float fast_sigmoid(float x) {
    return 1.0f / (1.0f + __expf(-x));
}
__device__ __forceinline__ float fast_tanh(float x) {
    float x2 = fminf(fmaxf(2.0f * x, -30.0f), 30.0f);
    float e = __expf(x2);
    return (e - 1.0f) / (e + 1.0f);
}

// Repack W_hh [4096 x 1024] fp32 -> fp16 MFMA B-fragment order, split into
// W_lds (ki 0..19, per slot 81920 halves, read once at startup) and
// W_l2 (ki 20..31, per j-block 24576 halves; ki 20..27 get register-pinned,
// ki 28..31 stream from L2 each step -> hot set only 1 MB/XCD).
__global__ void pack_w(const float* __restrict__ Whh,
                       _Float16* __restrict__ Wlds, _Float16* __restrict__ Wl2) {
    int idx = blockIdx.x * blockDim.x + threadIdx.x;   // over 4096*1024
    int gc = idx >> 10, k = idx & 1023;
    int nt = gc >> 10, u = gc & 1023;
    int jb = u >> 4, lk = u & 15;
    int ki = k >> 5, hi = (k >> 3) & 3, e = k & 7;
    int l = hi * 16 + lk;
    _Float16 v = (_Float16)Whh[idx];
    int frag = nt * 512 + l * 8 + e;
    if (ki < KL_) {
        int slot = jb >> 1, wj = jb & 1;
        Wlds[(size_t)slot * 81920 + wj * 40960 + ki * 2048 + frag] = v;
    } else {
        Wl2[(size_t)jb * 24576 + (ki - KL_) * 2048 + frag] = v;
    }
}

__global__ void init_misc(const float* __restrict__ bih, const float* __restrict__ bhh,
                          const float* __restrict__ bout,
                          float* __restrict__ bias, float* __restrict__ out) {
    int idx = blockIdx.x * blockDim.x + threadIdx.x;   // 131072 threads
    if (idx < G4_) bias[idx] = bih[idx] + bhh[idx];
    if (idx < B_ * T_) out[idx] = bout[0];
}

// Persistent kernel, 256 WGs x 512 thr (1 WG/CU). Batch across XCDs (64 rows
// each, zero cross-XCD traffic). Per XCD: 32 WGs x 32 hidden units; W ki 0..19
// in LDS (160 KB), ki 20..27 pinned in VGPRs (128/lane), ki 28..31 streamed
// from L2. h double-buffered; c in VGPRs; XCD-local barrier + L1 invalidate.
__global__ __launch_bounds__(512, 2)
void lstm_persist(const _Float16* __restrict__ Wlds,
                  const _Float16* __restrict__ Wl2,
                  const float* __restrict__ bias,
                  const float* __restrict__ x,
                  const float* __restrict__ Wih,
                  const float* __restrict__ Wout,
                  _Float16* __restrict__ hbuf,        // [8 xcd][2 phase][65536 halves]
                  float* __restrict__ out,
                  unsigned int* __restrict__ cnts) {  // [xcd] slot ctr, [16+xcd*32] barrier,
                                                      // [512+blk] slotmap
    extern __shared__ _Float16 Wl[];   // 81920 halves = 160 KB (full CU LDS)
    cooperative_groups::grid_group grid = cooperative_groups::this_grid();

    const int tid = threadIdx.x;
    unsigned int xcc;
    asm volatile("s_getreg_b32 %0, hwreg(HW_REG_XCC_ID)" : "=s"(xcc));
    const int xcd = (int)(xcc & 7u);
    if (tid == 0) {
        unsigned int s = __hip_atomic_fetch_add(&cnts[xcd], 1u,
                                                __ATOMIC_RELAXED, __HIP_MEMORY_SCOPE_AGENT);
        __hip_atomic_store(&cnts[512 + blockIdx.x], s,
                           __ATOMIC_RELAXED, __HIP_MEMORY_SCOPE_AGENT);
    }
    grid.sync();   // one-time registration sync (also publishes slotmap)
    const int slot = (int)__hip_atomic_load(&cnts[512 + blockIdx.x],
                                            __ATOMIC_RELAXED, __HIP_MEMORY_SCOPE_AGENT);
    const int nactive = (int)min(32u, __hip_atomic_load(&cnts[xcd], __ATOMIC_RELAXED,
                                                        __HIP_MEMORY_SCOPE_AGENT));
    if (slot >= 32) return;

    const int w = tid >> 6, l = tid & 63;
    const int lk = l & 15, hi = l >> 4;
    const int wr = w >> 1, wj = w & 1;        // 4 row-blocks x 2 u-blocks
    const int row0 = wr * 16;                 // local row base (0..48)
    const int u = slot * 32 + wj * 16 + lk;   // hidden unit for this lane

    // one-time: this slot's W ki 0..19 -> LDS (81920 halves = 10240 half8)
    {
        const half8* src = (const half8*)(Wlds + (size_t)slot * 81920);
        half8* dst = (half8*)Wl;
#pragma unroll
        for (int o = 0; o < 20; ++o) dst[tid + o * 512] = src[tid + o * 512];
    }
    const _Float16* Bg = Wl2 + ((size_t)slot * 2 + wj) * 24576 + l * 8;
    // one-time: pin ki 20..27 B-fragments in registers (128 VGPRs/lane)
    half8 breg[KR_ * 4];
#pragma unroll
    for (int kg = 0; kg < KR_; ++kg)
#pragma unroll
        for (int nt = 0; nt < 4; ++nt)
            breg[kg * 4 + nt] = *(const half8*)(Bg + kg * 2048 + nt * 512);

    // one-time per-thread constants
    float bz[4], wi4[4];
#pragma unroll
    for (int nt = 0; nt < 4; ++nt) {
        int gc = nt * 1024 + u;
        bz[nt] = bias[gc];
        wi4[nt] = Wih[gc];
    }
    const float wout = Wout[u];
    int rowsl[4], rowsg[4];
#pragma unroll
    for (int r = 0; r < 4; ++r) {
        rowsl[r] = row0 + hi * 4 + r;
        rowsg[r] = xcd * 64 + rowsl[r];
    }
    const int kb = u >> 3, ue = u & 7;
    f32x4 creg = {0.f, 0.f, 0.f, 0.f};
    __syncthreads();

    _Float16* hx = hbuf + (size_t)xcd * 2 * 65536;
    const _Float16* Bgs = Bg + KR_ * 2048;   // streamed slices ki 28..31
    unsigned int* barp = &cnts[16 + xcd * 32];

    for (int t = 0; t < T_; ++t) {
        const int wb = t & 1, rb = wb ^ 1;
        f32x4 acc[4];
        float xv[4];
#pragma unroll
        for (int r = 0; r < 4; ++r) xv[r] = x[rowsg[r] * T_ + t];
#pragma unroll
        for (int nt = 0; nt < 4; ++nt) {
#pragma unroll
            for (int r = 0; r < 4; ++r) acc[nt][r] = bz[nt] + xv[r] * wi4[nt];
        }

        if (t > 0) {
            const _Float16* Ap = hx + rb * 65536 + hi * 512 + (row0 + lk) * 8;
            // stream loads for ki 28,29 issue now; consumed at the very end
            half8 bs[8];
#pragma unroll
            for (int q = 0; q < 8; ++q)
                bs[q] = *(const half8*)(Bgs + (q >> 2) * 2048 + (q & 3) * 512);
            // LDS k-slices 0..9
#pragma unroll
            for (int ki = 0; ki < 10; ++ki) {
                half8 a = *(const half8*)(Ap + ki * 2048);
                const _Float16* bp = Wl + wj * 40960 + ki * 2048 + l * 8;
#pragma unroll
                for (int nt = 0; nt < 4; ++nt) {
                    half8 b = *(const half8*)(bp + nt * 512);
                    acc[nt] = __builtin_amdgcn_mfma_f32_16x16x32_f16(a, b, acc[nt], 0, 0, 0);
                }
            }
            // stream loads for ki 30,31
            half8 bs2[8];
#pragma unroll
            for (int q = 0; q < 8; ++q)
                bs2[q] = *(const half8*)(Bgs + (2 + (q >> 2)) * 2048 + (q & 3) * 512);
            // LDS k-slices 10..19
#pragma unroll
            for (int ki = 10; ki < KL_; ++ki) {
                half8 a = *(const half8*)(Ap + ki * 2048);
                const _Float16* bp = Wl + wj * 40960 + ki * 2048 + l * 8;
#pragma unroll
                for (int nt = 0; nt < 4; ++nt) {
                    half8 b = *(const half8*)(bp + nt * 512);
                    acc[nt] = __builtin_amdgcn_mfma_f32_16x16x32_f16(a, b, acc[nt], 0, 0, 0);
                }
            }
            // register-pinned k-slices 20..27
#pragma unroll
            for (int kg = 0; kg < KR_; ++kg) {
                half8 a = *(const half8*)(Ap + (KL_ + kg) * 2048);
#pragma unroll
                for (int nt = 0; nt < 4; ++nt)
                    acc[nt] = __builtin_amdgcn_mfma_f32_16x16x32_f16(a, breg[kg * 4 + nt], acc[nt], 0, 0, 0);
            }
            // streamed k-slices 28..31 (loads long in flight)
#pragma unroll
            for (int kg = 0; kg < 2; ++kg) {
                half8 a = *(const half8*)(Ap + (KL_ + KR_ + kg) * 2048);
#pragma unroll
                for (int nt = 0; nt < 4; ++nt)
                    acc[nt] = __builtin_amdgcn_mfma_f32_16x16x32_f16(a, bs[kg * 4 + nt], acc[nt], 0, 0, 0);
            }
#pragma unroll
            for (int kg = 0; kg < 2; ++kg) {
                half8 a = *(const half8*)(Ap + (KL_ + KR_ + 2 + kg) * 2048);
#pragma unroll
                for (int nt = 0; nt < 4; ++nt)
                    acc[nt] = __builtin_amdgcn_mfma_f32_16x16x32_f16(a, bs2[kg * 4 + nt], acc[nt], 0, 0, 0);
            }
        }

        // elementwise LSTM update; acc[0..3] = i,f,g,o
        _Float16* hn = hx + wb * 65536;
        float p4[4];
#pragma unroll
        for (int r = 0; r < 4; ++r) {
            float iv = fast_sigmoid(acc[0][r]);
            float fv = fast_sigmoid(acc[1][r]);
            float gv = fast_tanh(acc[2][r]);
            float ov = fast_sigmoid(acc[3][r]);
            float cv = fv * creg[r] + iv * gv;
            creg[r] = cv;
            float hv = ov * fast_tanh(cv);
            hn[(kb * 64 + rowsl[r]) * 8 + ue] = (_Float16)hv;
            p4[r] = hv * wout;
        }
#pragma unroll
        for (int m = 1; m <= 8; m <<= 1) {
#pragma unroll
            for (int r = 0; r < 4; ++r) p4[r] += __shfl_xor(p4[r], m);
        }
        if (lk == 0) {
#pragma unroll
            for (int r = 0; r < 4; ++r)
                atomicAdd(&out[rowsg[r] * T_ + t], p4[r]);
        }

        if (t < T_ - 1) {
            // XCD-local barrier: syncthreads drains this WG's vmem into the
            // XCD's L2; one lane arrives + spins; then L1-only invalidate.
            __syncthreads();
            if (tid == 0) {
                __hip_atomic_fetch_add(barp, 1u, __ATOMIC_RELAXED, __HIP_MEMORY_SCOPE_AGENT);
                unsigned int tgt = (unsigned int)nactive * (unsigned int)(t + 1);
                while (__hip_atomic_load(barp, __ATOMIC_RELAXED, __HIP_MEMORY_SCOPE_AGENT) < tgt)
                    __builtin_amdgcn_s_sleep(2);
            }
            __syncthreads();
            asm volatile("buffer_inv sc0" ::: "memory");   // drop stale L1 lines
        }
    }
}

extern "C" void kernel_launch(void* const* d_in, const int* in_sizes, int n_in,
                              void* d_out, int out_size, void* d_ws, size_t ws_size,
                              hipStream_t stream) {
    const float* x    = (const float*)d_in[0];
    const float* Wih  = (const float*)d_in[1];
    const float* Whh  = (const float*)d_in[2];
    const float* bih  = (const float*)d_in[3];
    const float* bhh  = (const float*)d_in[4];
    const float* Wout = (const float*)d_in[5];
    const float* bout = (const float*)d_in[6];
    float* out = (float*)d_out;

    char* ws = (char*)d_ws;
    _Float16* Wlds = (_Float16*)ws;                        // 5 MB (32 x 160 KB)
    _Float16* Wl2  = (_Float16*)(ws + 5242880);            // 3 MB (64 x 48 KB)
    _Float16* hbuf = (_Float16*)(ws + (8 << 20));          // 2 MB (8 xcd x 2 x 128 KB)
    float* bias    = (float*)(ws + (10 << 20));            // 16 KB
    unsigned int* cnts = (unsigned int*)(ws + (10 << 20) + (64 << 10));  // 4 KB

    hipMemsetAsync(cnts, 0, 4096, stream);
    pack_w<<<(G4_ * H_) / 256, 256, 0, stream>>>(Whh, Wlds, Wl2);
    init_misc<<<512, 256, 0, stream>>>(bih, bhh, bout, bias, out);

    (void)hipFuncSetAttribute((const void*)lstm_persist,
                              hipFuncAttributeMaxDynamicSharedMemorySize, 163840);
    void* args[] = {&Wlds, &Wl2, &bias, &x, &Wih, &Wout, &hbuf, &out, &cnts};
    hipLaunchCooperativeKernel((void*)lstm_persist, dim3(256), dim3(512),
                               args, 163840, stream);
}

// Round 7
// 1786.756 us; speedup vs baseline: 16.6087x; 1.0526x over previous
//
#include <hip/hip_runtime.h>
#include <hip/hip_fp16.h>
#include <hip/hip_cooperative_groups.h>

#define B_ 512
#define T_ 256
#define H_ 1024
#define G4_ 4096
#define KL_ 20   // k-slices (of 32) resident in LDS
#define KR_ 8    // k-slices pinned in registers (ki 20..27)
#define KS_ 4    // k-slices streamed from L2 (ki 28..31)

typedef _Float16 half8 __attribute__((ext_vector_type(8)));
typedef float f32x4 __attribute__((ext_vector_type(4)));

__device__ __forceinline__ float fast_sigmoid(float x) {
    return 1.0f / (1.0f + __expf(-x));
}
__device__ __forceinline__ float fast_tanh(float x) {
    float x2 = fminf(fmaxf(2.0f * x, -30.0f), 30.0f);
    float e = __expf(x2);
    return (e - 1.0f) / (e + 1.0f);
}

// Repack W_hh [4096 x 1024] fp32 -> fp16 MFMA B-fragment order, split into
// W_lds (ki 0..19, per slot 81920 halves, read once at startup) and
// W_l2 (ki 20..31, per j-block 24576 halves; ki 20..27 register-pinned,
// ki 28..31 streamed from L2 each step).
__global__ void pack_w(const float* __restrict__ Whh,
                       _Float16* __restrict__ Wlds, _Float16* __restrict__ Wl2) {
    int idx = blockIdx.x * blockDim.x + threadIdx.x;   // over 4096*1024
    int gc = idx >> 10, k = idx & 1023;
    int nt = gc >> 10, u = gc & 1023;
    int jb = u >> 4, lk = u & 15;
    int ki = k >> 5, hi = (k >> 3) & 3, e = k & 7;
    int l = hi * 16 + lk;
    _Float16 v = (_Float16)Whh[idx];
    int frag = nt * 512 + l * 8 + e;
    if (ki < KL_) {
        int slot = jb >> 1, wj = jb & 1;
        Wlds[(size_t)slot * 81920 + wj * 40960 + ki * 2048 + frag] = v;
    } else {
        Wl2[(size_t)jb * 24576 + (ki - KL_) * 2048 + frag] = v;
    }
}

__global__ void init_misc(const float* __restrict__ bih, const float* __restrict__ bhh,
                          const float* __restrict__ bout,
                          float* __restrict__ bias, float* __restrict__ out) {
    int idx = blockIdx.x * blockDim.x + threadIdx.x;   // 131072 threads
    if (idx < G4_) bias[idx] = bih[idx] + bhh[idx];
    if (idx < B_ * T_) out[idx] = bout[0];
}

// Persistent kernel, 256 WGs x 512 thr (1 WG/CU). Batch across XCDs (64 rows
// each, zero cross-XCD traffic). Per XCD: 32 WGs x 32 hidden units; W ki 0..19
// in LDS (160 KB), ki 20..27 FORCE-pinned in VGPRs (asm opaque barrier),
// ki 28..31 streamed from L2. h double-buffered; c in VGPRs; XCD-local
// split arrive/wait barrier + L1 invalidate.
__global__ __launch_bounds__(512, 2)
void lstm_persist(const _Float16* __restrict__ Wlds,
                  const _Float16* __restrict__ Wl2,
                  const float* __restrict__ bias,
                  const float* __restrict__ x,
                  const float* __restrict__ Wih,
                  const float* __restrict__ Wout,
                  _Float16* __restrict__ hbuf,        // [8 xcd][2 phase][65536 halves]
                  float* __restrict__ out,
                  unsigned int* __restrict__ cnts) {  // [xcd] slot ctr, [16+xcd*32] barrier,
                                                      // [512+blk] slotmap
    extern __shared__ _Float16 Wl[];   // 81920 halves = 160 KB (full CU LDS)
    cooperative_groups::grid_group grid = cooperative_groups::this_grid();

    const int tid = threadIdx.x;
    unsigned int xcc;
    asm volatile("s_getreg_b32 %0, hwreg(HW_REG_XCC_ID)" : "=s"(xcc));
    const int xcd = (int)(xcc & 7u);
    if (tid == 0) {
        unsigned int s = __hip_atomic_fetch_add(&cnts[xcd], 1u,
                                                __ATOMIC_RELAXED, __HIP_MEMORY_SCOPE_AGENT);
        __hip_atomic_store(&cnts[512 + blockIdx.x], s,
                           __ATOMIC_RELAXED, __HIP_MEMORY_SCOPE_AGENT);
    }
    grid.sync();   // one-time registration sync (also publishes slotmap)
    const int slot = (int)__hip_atomic_load(&cnts[512 + blockIdx.x],
                                            __ATOMIC_RELAXED, __HIP_MEMORY_SCOPE_AGENT);
    const int nactive = (int)min(32u, __hip_atomic_load(&cnts[xcd], __ATOMIC_RELAXED,
                                                        __HIP_MEMORY_SCOPE_AGENT));
    if (slot >= 32) return;

    const int w = tid >> 6, l = tid & 63;
    const int lk = l & 15, hi = l >> 4;
    const int wr = w >> 1, wj = w & 1;        // 4 row-blocks x 2 u-blocks
    const int row0 = wr * 16;                 // local row base (0..48)
    const int u = slot * 32 + wj * 16 + lk;   // hidden unit for this lane

    // one-time: this slot's W ki 0..19 -> LDS (81920 halves = 10240 half8)
    {
        const half8* src = (const half8*)(Wlds + (size_t)slot * 81920);
        half8* dst = (half8*)Wl;
#pragma unroll
        for (int o = 0; o < 20; ++o) dst[tid + o * 512] = src[tid + o * 512];
    }
    const _Float16* Bg = Wl2 + ((size_t)slot * 2 + wj) * 24576 + l * 8;
    // one-time: pin ki 20..27 B-fragments in registers (128 VGPRs/lane).
    // The empty asm redefines each value -> compiler cannot rematerialize
    // the loads inside the t-loop; values stay live in VGPRs.
    half8 breg[KR_ * 4];
#pragma unroll
    for (int kg = 0; kg < KR_; ++kg)
#pragma unroll
        for (int nt = 0; nt < 4; ++nt)
            breg[kg * 4 + nt] = *(const half8*)(Bg + kg * 2048 + nt * 512);
#pragma unroll
    for (int q = 0; q < KR_ * 4; ++q) asm volatile("" : "+v"(breg[q]));

    // one-time per-thread constants
    float bz[4], wi4[4];
#pragma unroll
    for (int nt = 0; nt < 4; ++nt) {
        int gc = nt * 1024 + u;
        bz[nt] = bias[gc];
        wi4[nt] = Wih[gc];
    }
    const float wout = Wout[u];
    int rowsl[4], rowsg[4];
#pragma unroll
    for (int r = 0; r < 4; ++r) {
        rowsl[r] = row0 + hi * 4 + r;
        rowsg[r] = xcd * 64 + rowsl[r];
    }
    const int kb = u >> 3, ue = u & 7;
    f32x4 creg = {0.f, 0.f, 0.f, 0.f};
    __syncthreads();

    _Float16* hx = hbuf + (size_t)xcd * 2 * 65536;
    const _Float16* Bgs = Bg + KR_ * 2048;   // streamed slices ki 28..31
    unsigned int* barp = &cnts[16 + xcd * 32];

    // x for t=0 preloaded; subsequent steps prefetch between arrive and wait
    float xv[4];
#pragma unroll
    for (int r = 0; r < 4; ++r) xv[r] = x[rowsg[r] * T_];

    for (int t = 0; t < T_; ++t) {
        // -------- wait phase (h(t-1) from all slots visible) --------
        if (t > 0) {
            if (tid == 0) {
                unsigned int tgt = (unsigned int)nactive * (unsigned int)t;
                while (__hip_atomic_load(barp, __ATOMIC_RELAXED, __HIP_MEMORY_SCOPE_AGENT) < tgt)
                    __builtin_amdgcn_s_sleep(2);
            }
            __syncthreads();
            asm volatile("buffer_inv sc0" ::: "memory");   // drop stale L1 lines
        }

        const int wb = t & 1, rb = wb ^ 1;
        f32x4 acc[4];
#pragma unroll
        for (int nt = 0; nt < 4; ++nt) {
#pragma unroll
            for (int r = 0; r < 4; ++r) acc[nt][r] = bz[nt] + xv[r] * wi4[nt];
        }

        if (t > 0) {
            const _Float16* Ap = hx + rb * 65536 + hi * 512 + (row0 + lk) * 8;
            // stream loads for ki 28,29 issue now; consumed at the very end
            half8 bs[8];
#pragma unroll
            for (int q = 0; q < 8; ++q)
                bs[q] = *(const half8*)(Bgs + (q >> 2) * 2048 + (q & 3) * 512);
            // LDS k-slices 0..9
#pragma unroll
            for (int ki = 0; ki < 10; ++ki) {
                half8 a = *(const half8*)(Ap + ki * 2048);
                const _Float16* bp = Wl + wj * 40960 + ki * 2048 + l * 8;
#pragma unroll
                for (int nt = 0; nt < 4; ++nt) {
                    half8 b = *(const half8*)(bp + nt * 512);
                    acc[nt] = __builtin_amdgcn_mfma_f32_16x16x32_f16(a, b, acc[nt], 0, 0, 0);
                }
            }
            // stream loads for ki 30,31
            half8 bs2[8];
#pragma unroll
            for (int q = 0; q < 8; ++q)
                bs2[q] = *(const half8*)(Bgs + (2 + (q >> 2)) * 2048 + (q & 3) * 512);
            // LDS k-slices 10..19
#pragma unroll
            for (int ki = 10; ki < KL_; ++ki) {
                half8 a = *(const half8*)(Ap + ki * 2048);
                const _Float16* bp = Wl + wj * 40960 + ki * 2048 + l * 8;
#pragma unroll
                for (int nt = 0; nt < 4; ++nt) {
                    half8 b = *(const half8*)(bp + nt * 512);
                    acc[nt] = __builtin_amdgcn_mfma_f32_16x16x32_f16(a, b, acc[nt], 0, 0, 0);
                }
            }
            // register-pinned k-slices 20..27
#pragma unroll
            for (int kg = 0; kg < KR_; ++kg) {
                half8 a = *(const half8*)(Ap + (KL_ + kg) * 2048);
#pragma unroll
                for (int nt = 0; nt < 4; ++nt)
                    acc[nt] = __builtin_amdgcn_mfma_f32_16x16x32_f16(a, breg[kg * 4 + nt], acc[nt], 0, 0, 0);
            }
            // streamed k-slices 28..31 (loads long in flight)
#pragma unroll
            for (int kg = 0; kg < 2; ++kg) {
                half8 a = *(const half8*)(Ap + (KL_ + KR_ + kg) * 2048);
#pragma unroll
                for (int nt = 0; nt < 4; ++nt)
                    acc[nt] = __builtin_amdgcn_mfma_f32_16x16x32_f16(a, bs[kg * 4 + nt], acc[nt], 0, 0, 0);
            }
#pragma unroll
            for (int kg = 0; kg < 2; ++kg) {
                half8 a = *(const half8*)(Ap + (KL_ + KR_ + 2 + kg) * 2048);
#pragma unroll
                for (int nt = 0; nt < 4; ++nt)
                    acc[nt] = __builtin_amdgcn_mfma_f32_16x16x32_f16(a, bs2[kg * 4 + nt], acc[nt], 0, 0, 0);
            }
        }

        // elementwise LSTM update; acc[0..3] = i,f,g,o
        _Float16* hn = hx + wb * 65536;
        float p4[4];
#pragma unroll
        for (int r = 0; r < 4; ++r) {
            float iv = fast_sigmoid(acc[0][r]);
            float fv = fast_sigmoid(acc[1][r]);
            float gv = fast_tanh(acc[2][r]);
            float ov = fast_sigmoid(acc[3][r]);
            float cv = fv * creg[r] + iv * gv;
            creg[r] = cv;
            float hv = ov * fast_tanh(cv);
            hn[(kb * 64 + rowsl[r]) * 8 + ue] = (_Float16)hv;
            p4[r] = hv * wout;
        }

        // -------- arrive phase: h stores drained by syncthreads, then signal --------
        if (t < T_ - 1) {
            __syncthreads();   // compiler emits s_waitcnt vmcnt(0) per wave first
            if (tid == 0)
                __hip_atomic_fetch_add(barp, 1u, __ATOMIC_RELAXED, __HIP_MEMORY_SCOPE_AGENT);
        }

        // barrier-latency hiding: out projection + x prefetch for t+1
#pragma unroll
        for (int m = 1; m <= 8; m <<= 1) {
#pragma unroll
            for (int r = 0; r < 4; ++r) p4[r] += __shfl_xor(p4[r], m);
        }
        if (lk == 0) {
#pragma unroll
            for (int r = 0; r < 4; ++r)
                atomicAdd(&out[rowsg[r] * T_ + t], p4[r]);
        }
        if (t < T_ - 1) {
#pragma unroll
            for (int r = 0; r < 4; ++r) xv[r] = x[rowsg[r] * T_ + t + 1];
        }
    }
}

extern "C" void kernel_launch(void* const* d_in, const int* in_sizes, int n_in,
                              void* d_out, int out_size, void* d_ws, size_t ws_size,
                              hipStream_t stream) {
    const float* x    = (const float*)d_in[0];
    const float* Wih  = (const float*)d_in[1];
    const float* Whh  = (const float*)d_in[2];
    const float* bih  = (const float*)d_in[3];
    const float* bhh  = (const float*)d_in[4];
    const float* Wout = (const float*)d_in[5];
    const float* bout = (const float*)d_in[6];
    float* out = (float*)d_out;

    char* ws = (char*)d_ws;
    _Float16* Wlds = (_Float16*)ws;                        // 5 MB (32 x 160 KB)
    _Float16* Wl2  = (_Float16*)(ws + 5242880);            // 3 MB (64 x 48 KB)
    _Float16* hbuf = (_Float16*)(ws + (8 << 20));          // 2 MB (8 xcd x 2 x 128 KB)
    float* bias    = (float*)(ws + (10 << 20));            // 16 KB
    unsigned int* cnts = (unsigned int*)(ws + (10 << 20) + (64 << 10));  // 4 KB

    hipMemsetAsync(cnts, 0, 4096, stream);
    pack_w<<<(G4_ * H_) / 256, 256, 0, stream>>>(Whh, Wlds, Wl2);
    init_misc<<<512, 256, 0, stream>>>(bih, bhh, bout, bias, out);

    (void)hipFuncSetAttribute((const void*)lstm_persist,
                              hipFuncAttributeMaxDynamicSharedMemorySize, 163840);
    void* args[] = {&Wlds, &Wl2, &bias, &x, &Wih, &Wout, &hbuf, &out, &cnts};
    hipLaunchCooperativeKernel((void*)lstm_persist, dim3(256), dim3(512),
                               args, 163840, stream);
}